// Round 2
// baseline (426.931 us; speedup 1.0000x reference)
//
#include <hip/hip_runtime.h>
#include <hip/hip_bf16.h>
#include <math.h>

using bf16 = __hip_bfloat16;
typedef __attribute__((ext_vector_type(8))) short short8;
typedef __attribute__((ext_vector_type(4))) float float4v;

#define BM 128
#define BN 128
#define BK 64
#define LDK 72   // BK + 8 bf16 pad -> row stride 144B, breaks power-of-2 bank strides

template <typename T> __device__ inline T cvt_out(float v);
template <> __device__ inline float cvt_out<float>(float v) { return v; }
template <> __device__ inline bf16 cvt_out<bf16>(float v) { return __float2bfloat16(v); }

// fp32 -> bf16 bulk convert, 4 elems/thread
__global__ __launch_bounds__(256) void cvt_f32_bf16(const float* __restrict__ in,
                                                    bf16* __restrict__ out, int n) {
    int i = (blockIdx.x * blockDim.x + threadIdx.x) * 4;
    if (i < n) {
        float4 v = *(const float4*)(in + i);
        out[i + 0] = __float2bfloat16(v.x);
        out[i + 1] = __float2bfloat16(v.y);
        out[i + 2] = __float2bfloat16(v.z);
        out[i + 3] = __float2bfloat16(v.w);
    }
}

// C[m][n] = act( sum_k A[m][k] * W[n][k] + bias[n] )
// ACT: 0=none, 1=relu, 2=tanh. A: (M,K) bf16 row-major. W: (N,K) bf16 row-major.
template <int ACT, typename OutT>
__global__ __launch_bounds__(256) void gemm_bt(const bf16* __restrict__ A,
                                               const bf16* __restrict__ W,
                                               const float* __restrict__ bias,
                                               OutT* __restrict__ C,
                                               int M, int N, int K) {
    __shared__ bf16 As[BM * LDK];
    __shared__ bf16 Bs[BN * LDK];

    const int tid = threadIdx.x;
    const int bm = blockIdx.y, bn = blockIdx.x;
    const int wave = tid >> 6, lane = tid & 63;
    const int wm = (wave >> 1) * 64, wn = (wave & 1) * 64;
    const int quad = lane >> 4, lrow = lane & 15;

    float4v acc[4][4] = {};

    for (int k0 = 0; k0 < K; k0 += BK) {
        __syncthreads();  // protect LDS from previous iteration's readers
#pragma unroll
        for (int t = 0; t < 4; ++t) {
            int c = tid + t * 256;            // 0..1023
            int row = c >> 3, col = (c & 7) * 8;
            short8 va = *(const short8*)(A + (size_t)(bm * BM + row) * K + k0 + col);
            *(short8*)(As + row * LDK + col) = va;
            short8 vb = *(const short8*)(W + (size_t)(bn * BN + row) * K + k0 + col);
            *(short8*)(Bs + row * LDK + col) = vb;
        }
        __syncthreads();
#pragma unroll
        for (int kk = 0; kk < BK; kk += 32) {
            short8 af[4], bfr[4];
#pragma unroll
            for (int i = 0; i < 4; ++i)
                af[i] = *(const short8*)(As + (wm + i * 16 + lrow) * LDK + kk + quad * 8);
#pragma unroll
            for (int j = 0; j < 4; ++j)
                bfr[j] = *(const short8*)(Bs + (wn + j * 16 + lrow) * LDK + kk + quad * 8);
#pragma unroll
            for (int i = 0; i < 4; ++i)
#pragma unroll
                for (int j = 0; j < 4; ++j)
                    acc[i][j] = __builtin_amdgcn_mfma_f32_16x16x32_bf16(af[i], bfr[j], acc[i][j], 0, 0, 0);
        }
    }

    // epilogue: C/D layout col=lane&15, row=quad*4+reg (m89/m91-verified)
#pragma unroll
    for (int i = 0; i < 4; ++i) {
        int m0 = bm * BM + wm + i * 16 + quad * 4;
#pragma unroll
        for (int j = 0; j < 4; ++j) {
            int n = bn * BN + wn + j * 16 + lrow;
            float bv = bias[n];
#pragma unroll
            for (int r = 0; r < 4; ++r) {
                float v = acc[i][j][r] + bv;
                if (ACT == 1) v = fmaxf(v, 0.f);
                else if (ACT == 2) v = tanhf(v);
                C[(size_t)(m0 + r) * N + n] = cvt_out<OutT>(v);
            }
        }
    }
}

// One wave per row: power-norm -> single-tap channel + noise -> LS h_est -> ZF.
// s: (B,256) fp32.  Writes xr as fp32 (for the FIR) and bf16 (for GEMM input).
__global__ __launch_bounds__(64) void channel_kernel(const float* __restrict__ s,
                                                     const float* __restrict__ h,
                                                     const float* __restrict__ noise,
                                                     float* __restrict__ xr_f,
                                                     bf16* __restrict__ xr_b) {
    const int b = blockIdx.x, lane = threadIdx.x;
    const float* srow = s + (size_t)b * 256;

    float ss = 0.f;
#pragma unroll
    for (int t = 0; t < 4; ++t) {
        float v = srow[lane + 64 * t];
        ss += v * v;
    }
#pragma unroll
    for (int off = 32; off; off >>= 1) ss += __shfl_xor(ss, off);
    const float inv = sqrtf(128.0f) / sqrtf(ss);  // sqrt(2n*0.5) / ||s||

    const float hre = h[0], him = h[1];

    float yre[2], yim[2];
    float nre = 0.f, nim = 0.f, den = 0.f;
#pragma unroll
    for (int t = 0; t < 2; ++t) {
        int c = lane + 64 * t;  // complex index 0..127
        float tr = srow[2 * c] * inv, ti = srow[2 * c + 1] * inv;
        float yr = hre * tr - him * ti + noise[(size_t)b * 256 + 2 * c];
        float yi = hre * ti + him * tr + noise[(size_t)b * 256 + 2 * c + 1];
        yre[t] = yr; yim[t] = yi;
        nre += yr * tr + yi * ti;   // y * conj(tx)
        nim += yi * tr - yr * ti;
        den += tr * tr + ti * ti;
    }
#pragma unroll
    for (int off = 32; off; off >>= 1) {
        nre += __shfl_xor(nre, off);
        nim += __shfl_xor(nim, off);
        den += __shfl_xor(den, off);
    }
    const float her = nre / den, hei = nim / den;
    const float d2 = her * her + hei * hei + 1e-12f;

#pragma unroll
    for (int t = 0; t < 2; ++t) {
        int c = lane + 64 * t;
        float xre = (yre[t] * her + yim[t] * hei) / d2;  // y * conj(h_est) / |h_est|^2
        float xim = (yim[t] * her - yre[t] * hei) / d2;
        xr_f[(size_t)b * 256 + 2 * c] = xre;
        xr_f[(size_t)b * 256 + 2 * c + 1] = xim;
        xr_b[(size_t)b * 256 + 2 * c] = __float2bfloat16(xre);
        xr_b[(size_t)b * 256 + 2 * c + 1] = __float2bfloat16(xim);
    }
}

// One wave per row: h_inv = g2 @ w_rtn3^T + b_rtn3 (N=6), then 3-tap causal
// complex FIR on xr (fp32), output bf16 for the decoder GEMM.
__global__ __launch_bounds__(64) void rtn_taps_conv(const bf16* __restrict__ g2,
                                                    const float* __restrict__ wr3,
                                                    const float* __restrict__ br3,
                                                    const float* __restrict__ xr_f,
                                                    bf16* __restrict__ xr2) {
    const int b = blockIdx.x, lane = threadIdx.x;
    const bf16* grow = g2 + (size_t)b * 1024;

    float acc[6] = {0.f, 0.f, 0.f, 0.f, 0.f, 0.f};
#pragma unroll
    for (int t = 0; t < 16; ++t) {
        int k = lane + 64 * t;
        float gv = __bfloat162float(grow[k]);
#pragma unroll
        for (int j = 0; j < 6; ++j) acc[j] += gv * wr3[j * 1024 + k];
    }
#pragma unroll
    for (int j = 0; j < 6; ++j)
#pragma unroll
        for (int off = 32; off; off >>= 1) acc[j] += __shfl_xor(acc[j], off);

    float tre[3], tim[3];
#pragma unroll
    for (int l = 0; l < 3; ++l) {
        tre[l] = acc[2 * l] + br3[2 * l];
        tim[l] = acc[2 * l + 1] + br3[2 * l + 1];
    }

    const float* xrow = xr_f + (size_t)b * 256;
#pragma unroll
    for (int t = 0; t < 2; ++t) {
        int c = lane + 64 * t;
        float ore = 0.f, oim = 0.f;
#pragma unroll
        for (int l = 0; l < 3; ++l) {
            int cc = c - l;
            if (cc >= 0) {
                float xre = xrow[2 * cc], xim = xrow[2 * cc + 1];
                ore += tre[l] * xre - tim[l] * xim;
                oim += tre[l] * xim + tim[l] * xre;
            }
        }
        xr2[(size_t)b * 256 + 2 * c] = __float2bfloat16(ore);
        xr2[(size_t)b * 256 + 2 * c + 1] = __float2bfloat16(oim);
    }
}

extern "C" void kernel_launch(void* const* d_in, const int* in_sizes, int n_in,
                              void* d_out, int out_size, void* d_ws, size_t ws_size,
                              hipStream_t stream) {
    constexpr int B = 8192, D_IN = 512, H1 = 4096, CH = 256, HR = 1024, H2 = 4096, DOUT = 512;

    const float* x   = (const float*)d_in[0];
    const float* w1  = (const float*)d_in[1];
    const float* b1  = (const float*)d_in[2];
    const float* w2  = (const float*)d_in[3];
    const float* b2  = (const float*)d_in[4];
    const float* wr1 = (const float*)d_in[5];
    const float* br1 = (const float*)d_in[6];
    const float* wr2 = (const float*)d_in[7];
    const float* br2 = (const float*)d_in[8];
    const float* wr3 = (const float*)d_in[9];
    const float* br3 = (const float*)d_in[10];
    const float* w3  = (const float*)d_in[11];
    const float* b3  = (const float*)d_in[12];
    const float* w4  = (const float*)d_in[13];
    const float* b4  = (const float*)d_in[14];
    const float* h   = (const float*)d_in[15];
    const float* noise = (const float*)d_in[16];

    // ---- workspace layout (bytes) ----
    char* ws = (char*)d_ws;
    bf16*  a    = (bf16*)(ws + 0);          // 64 MB: GEMM1 out; later reused: g1, g2, tbuf
    bf16*  g1   = (bf16*)(ws + 0);          // 16 MB (a is dead after GEMM2)
    bf16*  g2   = (bf16*)(ws + 16777216);   // 16 MB
    bf16*  tbuf = (bf16*)(ws + 0);          // 64 MB (g1/g2 dead after rtn_taps_conv)
    bf16*  xB   = (bf16*)(ws + 67108864);               // 8 MB  bf16(x)
    float* sF   = (float*)(ws + 75497472);              // 8 MB
    float* xrF  = (float*)(ws + 83886080);              // 8 MB
    bf16*  xrB  = (bf16*)(ws + 92274688);               // 4 MB
    bf16*  xr2  = (bf16*)(ws + 96468992);               // 4 MB
    bf16*  w1B  = (bf16*)(ws + 100663296);              // 4 MB
    bf16*  w2B  = (bf16*)(ws + 104857600);              // 2 MB
    bf16*  wr1B = (bf16*)(ws + 106954752);              // 0.5 MB
    bf16*  wr2B = (bf16*)(ws + 107479040);              // 2 MB
    bf16*  w3B  = (bf16*)(ws + 109576192);              // 2 MB
    bf16*  w4B  = (bf16*)(ws + 111673344);              // 4 MB  -> ends ~115.9 MB

    dim3 blk(256);

    // ---- fp32 -> bf16 conversions (x + 6 GEMM weights) ----
    auto cvt = [&](const float* src, bf16* dst, int n) {
        cvt_f32_bf16<<<(n / 4 + 255) / 256, blk, 0, stream>>>(src, dst, n);
    };
    cvt(x,   xB,   B * D_IN);
    cvt(w1,  w1B,  H1 * D_IN);
    cvt(w2,  w2B,  CH * H1);
    cvt(wr1, wr1B, HR * CH);
    cvt(wr2, wr2B, HR * HR);
    cvt(w3,  w3B,  H2 * CH);
    cvt(w4,  w4B,  DOUT * H2);

    // ---- encoder ----
    gemm_bt<1, bf16><<<dim3(H1 / BN, B / BM), blk, 0, stream>>>(xB, w1B, b1, a, B, H1, D_IN);
    gemm_bt<0, float><<<dim3(CH / BN, B / BM), blk, 0, stream>>>(a, w2B, b2, sF, B, CH, H1);
    // ---- channel + ZF (fp32) ----
    channel_kernel<<<B, 64, 0, stream>>>(sF, h, noise, xrF, xrB);
    // ---- RTN ----
    gemm_bt<2, bf16><<<dim3(HR / BN, B / BM), blk, 0, stream>>>(xrB, wr1B, br1, g1, B, HR, CH);
    gemm_bt<2, bf16><<<dim3(HR / BN, B / BM), blk, 0, stream>>>(g1, wr2B, br2, g2, B, HR, HR);
    rtn_taps_conv<<<B, 64, 0, stream>>>(g2, wr3, br3, xrF, xr2);
    // ---- decoder ----
    gemm_bt<1, bf16><<<dim3(H2 / BN, B / BM), blk, 0, stream>>>(xr2, w3B, b3, tbuf, B, H2, CH);
    gemm_bt<0, float><<<dim3(DOUT / BN, B / BM), blk, 0, stream>>>(tbuf, w4B, b4, (float*)d_out, B, DOUT, H2);
}